// Round 3
// baseline (2513.788 us; speedup 1.0000x reference)
//
#include <hip/hip_runtime.h>
#include <hip/hip_bf16.h>

#define N_NODE 512
#define N_GRAPH 8
#define EDIM 1024
#define NHEADS 16
#define HD 64
#define GH 128       // n_graph * NHEADS
#define MROWS 4096   // n_node * n_graph

__device__ __forceinline__ float bf2f(__hip_bfloat16 h) { return __bfloat162float(h); }

template<typename T> __device__ __forceinline__ float ldf(const T* p);
template<> __device__ __forceinline__ float ldf<float>(const float* p) { return *p; }
template<> __device__ __forceinline__ float ldf<__hip_bfloat16>(const __hip_bfloat16* p) { return bf2f(*p); }

template<typename T> __device__ __forceinline__ void stf(T* p, float v);
template<> __device__ __forceinline__ void stf<float>(float* p, float v) { *p = v; }
template<> __device__ __forceinline__ void stf<__hip_bfloat16>(__hip_bfloat16* p, float v) { *p = __float2bfloat16(v); }

__device__ __forceinline__ void load8(const float* p, float* d) {
    float4 a = *reinterpret_cast<const float4*>(p);
    float4 b = *reinterpret_cast<const float4*>(p + 4);
    d[0] = a.x; d[1] = a.y; d[2] = a.z; d[3] = a.w;
    d[4] = b.x; d[5] = b.y; d[6] = b.z; d[7] = b.w;
}
__device__ __forceinline__ void load8(const __hip_bfloat16* p, float* d) {
    union { uint4 u; __hip_bfloat16 h[8]; } v;
    v.u = *reinterpret_cast<const uint4*>(p);
    #pragma unroll
    for (int x = 0; x < 8; x++) d[x] = bf2f(v.h[x]);
}

// C = A @ B^T + bias.  A [M,K] row-major (TA), B [N,K] row-major fp32.
// MODE 0: write C row-major [M,N] fp32 into Cout.
// MODE 1: qkv scatter into Cq/Ck/Cv (type TS), each [GH, N_NODE, HD]; q scaled 0.125.
template<typename TA, typename TS, int MODE>
__global__ __launch_bounds__(256)
void gemm_nt(const TA* __restrict__ A,
             const float* __restrict__ B,
             const float* __restrict__ bias,
             float* __restrict__ Cout,
             TS* __restrict__ Cq,
             TS* __restrict__ Ck,
             TS* __restrict__ Cv,
             int M, int N, int K)
{
    __shared__ float As[64][33];
    __shared__ float Bs[64][33];
    const int tid = threadIdx.x;
    const int m0 = blockIdx.y * 64;
    const int n0 = blockIdx.x * 64;
    const int tm = tid >> 4;          // 0..15
    const int tn = tid & 15;          // 0..15
    const int lr = tid >> 2;          // 0..63 (row inside tile for loads)
    const int lc = (tid & 3) << 3;    // 0,8,16,24

    float acc[4][4] = {};

    for (int k0 = 0; k0 < K; k0 += 32) {
        float av[8], bv[8];
        load8(A + (size_t)(m0 + lr) * K + k0 + lc, av);
        load8(B + (size_t)(n0 + lr) * K + k0 + lc, bv);
        #pragma unroll
        for (int x = 0; x < 8; x++) {
            As[lr][lc + x] = av[x];
            Bs[lr][lc + x] = bv[x];
        }
        __syncthreads();
        #pragma unroll
        for (int kk = 0; kk < 32; kk++) {
            float a[4], b[4];
            #pragma unroll
            for (int x = 0; x < 4; x++) { a[x] = As[tm * 4 + x][kk]; b[x] = Bs[tn * 4 + x][kk]; }
            #pragma unroll
            for (int x = 0; x < 4; x++)
                #pragma unroll
                for (int y = 0; y < 4; y++)
                    acc[x][y] = fmaf(a[x], b[y], acc[x][y]);
        }
        __syncthreads();
    }

    #pragma unroll
    for (int x = 0; x < 4; x++) {
        const int r = m0 + tm * 4 + x;
        #pragma unroll
        for (int y = 0; y < 4; y++) {
            const int c = n0 + tn * 4 + y;
            float v = acc[x][y] + bias[c];
            if (MODE == 0) {
                Cout[(size_t)r * N + c] = v;
            } else {
                const int qsel = c >> 10;          // 0=q 1=k 2=v
                const int e = c & 1023;
                const int head = e >> 6;
                const int d = e & 63;
                const int node = r >> 3;
                const int graph = r & 7;
                const int b = graph * NHEADS + head;
                const size_t idx = ((size_t)b * N_NODE + node) * HD + d;
                if (qsel == 0) {
                    stf(Cq + idx, v * 0.125f);
                } else if (qsel == 1) {
                    stf(Ck + idx, v);
                } else {
                    stf(Cv + idx, v);
                }
            }
        }
    }
}

// One block per (batch b, query row i). 256 threads.
template<typename TS>
__global__ __launch_bounds__(256)
void attn_kernel(const TS* __restrict__ Q,
                 const TS* __restrict__ Kh,
                 const TS* __restrict__ Vh,
                 const float* __restrict__ bias,
                 const float* __restrict__ gaw,
                 TS* __restrict__ A2)
{
    const int b = blockIdx.y;     // 0..127
    const int i = blockIdx.x;     // 0..511
    const int t = threadIdx.x;    // 0..255
    const int lane = t & 63;
    const int wid = t >> 6;

    __shared__ float qs[64];
    __shared__ float ps[512];
    __shared__ float redm[4];
    __shared__ float reds[4];
    __shared__ float part[256];

    if (t < 64) qs[t] = ldf(Q + ((size_t)b * N_NODE + i) * HD + t);
    __syncthreads();

    const size_t rowoff = ((size_t)b * N_NODE + i) * N_NODE;

    float s[2];
    #pragma unroll
    for (int u = 0; u < 2; u++) {
        const int j = t + u * 256;
        const TS* krow = Kh + ((size_t)b * N_NODE + j) * HD;
        float dot = 0.f;
        #pragma unroll
        for (int d0 = 0; d0 < HD; d0 += 8) {
            float kv[8];
            load8(krow + d0, kv);
            #pragma unroll
            for (int x = 0; x < 8; x++) dot = fmaf(qs[d0 + x], kv[x], dot);
        }
        s[u] = dot + bias[rowoff + j];
    }

    // block max
    float m = fmaxf(s[0], s[1]);
    #pragma unroll
    for (int off = 32; off > 0; off >>= 1) m = fmaxf(m, __shfl_xor(m, off));
    if (lane == 0) redm[wid] = m;
    __syncthreads();
    m = fmaxf(fmaxf(redm[0], redm[1]), fmaxf(redm[2], redm[3]));

    float e0 = __expf(s[0] - m);
    float e1 = __expf(s[1] - m);
    float sum = e0 + e1;
    #pragma unroll
    for (int off = 32; off > 0; off >>= 1) sum += __shfl_xor(sum, off);
    if (lane == 0) reds[wid] = sum;
    __syncthreads();
    sum = reds[0] + reds[1] + reds[2] + reds[3];
    const float rs = 1.0f / sum;

    {
        const int j0 = t;
        const int j1 = t + 256;
        ps[j0] = tanhf(gaw[rowoff + j0]) * e0 * rs;
        ps[j1] = tanhf(gaw[rowoff + j1]) * e1 * rs;
    }
    __syncthreads();

    // P @ V : thread t covers d = t&63, j-range seg*128..seg*128+127
    const int d = t & 63;
    const int seg = t >> 6;
    float acc = 0.f;
    #pragma unroll 4
    for (int jo = 0; jo < 128; jo++) {
        const int j = seg * 128 + jo;
        acc = fmaf(ps[j], ldf(Vh + ((size_t)b * N_NODE + j) * HD + d), acc);
    }
    part[t] = acc;
    __syncthreads();

    if (t < 64) {
        const float o = part[t] + part[64 + t] + part[128 + t] + part[192 + t];
        const int graph = b >> 4;
        const int head = b & 15;
        stf(A2 + ((size_t)i * N_GRAPH + graph) * EDIM + head * HD + t, o);
    }
}

template<typename TS>
static void run_pipeline(const float* query, const float* attn_bias, const float* gaw,
                         const float* in_w, const float* in_b,
                         const float* out_w, const float* out_b,
                         float* out, void* d_ws, hipStream_t stream)
{
    TS* ws = (TS*)d_ws;
    const size_t hsz = (size_t)GH * N_NODE * HD;   // 4 Mi elements
    TS* Q  = ws;
    TS* K  = ws + hsz;
    TS* V  = ws + 2 * hsz;
    TS* A2 = ws + 3 * hsz;

    // 1) fused QKV projection + head-layout scatter
    {
        dim3 grid((3 * EDIM) / 64, MROWS / 64);   // (48, 64)
        gemm_nt<float, TS, 1><<<grid, 256, 0, stream>>>(query, in_w, in_b,
                                                        nullptr, Q, K, V,
                                                        MROWS, 3 * EDIM, EDIM);
    }
    // 2) attention
    {
        dim3 grid(N_NODE, GH);                    // (512, 128)
        attn_kernel<TS><<<grid, 256, 0, stream>>>(Q, K, V, attn_bias, gaw, A2);
    }
    // 3) output projection
    {
        dim3 grid(EDIM / 64, MROWS / 64);         // (16, 64)
        gemm_nt<TS, TS, 0><<<grid, 256, 0, stream>>>(A2, out_w, out_b,
                                                     out, nullptr, nullptr, nullptr,
                                                     MROWS, EDIM, EDIM);
    }
}

extern "C" void kernel_launch(void* const* d_in, const int* in_sizes, int n_in,
                              void* d_out, int out_size, void* d_ws, size_t ws_size,
                              hipStream_t stream) {
    const float* query     = (const float*)d_in[0];
    const float* attn_bias = (const float*)d_in[1];
    const float* gaw       = (const float*)d_in[2];
    const float* in_w      = (const float*)d_in[3];
    const float* in_b      = (const float*)d_in[4];
    const float* out_w     = (const float*)d_in[5];
    const float* out_b     = (const float*)d_in[6];
    float* out = (float*)d_out;

    const size_t hsz = (size_t)GH * N_NODE * HD;   // 4 Mi elements
    const size_t need_f32 = 4 * hsz * sizeof(float);   // 64 MiB

    if (ws_size >= need_f32) {
        run_pipeline<float>(query, attn_bias, gaw, in_w, in_b, out_w, out_b,
                            out, d_ws, stream);
    } else {
        run_pipeline<__hip_bfloat16>(query, attn_bias, gaw, in_w, in_b, out_w, out_b,
                                     out, d_ws, stream);
    }
}

// Round 4
// 1019.259 us; speedup vs baseline: 2.4663x; 2.4663x over previous
//
#include <hip/hip_runtime.h>
#include <hip/hip_bf16.h>

#define N_NODE 512
#define N_GRAPH 8
#define EDIM 1024
#define NHEADS 16
#define HD 64
#define GH 128       // n_graph * NHEADS
#define MROWS 4096   // n_node * n_graph

typedef short bf16x8 __attribute__((ext_vector_type(8)));
typedef float f32x4  __attribute__((ext_vector_type(4)));

__device__ __forceinline__ float bf2f(__hip_bfloat16 h) { return __bfloat162float(h); }
__device__ __forceinline__ short f2bs(float f) {
    union { __hip_bfloat16 h; short s; } u; u.h = __float2bfloat16(f); return u.s;
}

__device__ __forceinline__ void load8(const float* p, float* d) {
    float4 a = *reinterpret_cast<const float4*>(p);
    float4 b = *reinterpret_cast<const float4*>(p + 4);
    d[0] = a.x; d[1] = a.y; d[2] = a.z; d[3] = a.w;
    d[4] = b.x; d[5] = b.y; d[6] = b.z; d[7] = b.w;
}
__device__ __forceinline__ void load8(const __hip_bfloat16* p, float* d) {
    union { uint4 u; __hip_bfloat16 h[8]; } v;
    v.u = *reinterpret_cast<const uint4*>(p);
    #pragma unroll
    for (int x = 0; x < 8; x++) d[x] = bf2f(v.h[x]);
}

// ---------------- GEMM (unchanged VALU version, bf16 intermediates) ----------
// C = A @ B^T + bias.  A [M,K] row-major (TA), B [N,K] row-major fp32.
// MODE 0: write C row-major [M,N] fp32 into Cout.
// MODE 1: qkv scatter into Cq/Ck/Cv bf16, each [GH, N_NODE, HD]; q scaled 0.125.
template<typename TA, int MODE>
__global__ __launch_bounds__(256)
void gemm_nt(const TA* __restrict__ A,
             const float* __restrict__ B,
             const float* __restrict__ bias,
             float* __restrict__ Cout,
             __hip_bfloat16* __restrict__ Cq,
             __hip_bfloat16* __restrict__ Ck,
             __hip_bfloat16* __restrict__ Cv,
             int M, int N, int K)
{
    __shared__ float As[64][33];
    __shared__ float Bs[64][33];
    const int tid = threadIdx.x;
    const int m0 = blockIdx.y * 64;
    const int n0 = blockIdx.x * 64;
    const int tm = tid >> 4;
    const int tn = tid & 15;
    const int lr = tid >> 2;
    const int lc = (tid & 3) << 3;

    float acc[4][4] = {};

    for (int k0 = 0; k0 < K; k0 += 32) {
        float av[8], bv[8];
        load8(A + (size_t)(m0 + lr) * K + k0 + lc, av);
        load8(B + (size_t)(n0 + lr) * K + k0 + lc, bv);
        #pragma unroll
        for (int x = 0; x < 8; x++) {
            As[lr][lc + x] = av[x];
            Bs[lr][lc + x] = bv[x];
        }
        __syncthreads();
        #pragma unroll
        for (int kk = 0; kk < 32; kk++) {
            float a[4], b[4];
            #pragma unroll
            for (int x = 0; x < 4; x++) { a[x] = As[tm * 4 + x][kk]; b[x] = Bs[tn * 4 + x][kk]; }
            #pragma unroll
            for (int x = 0; x < 4; x++)
                #pragma unroll
                for (int y = 0; y < 4; y++)
                    acc[x][y] = fmaf(a[x], b[y], acc[x][y]);
        }
        __syncthreads();
    }

    #pragma unroll
    for (int x = 0; x < 4; x++) {
        const int r = m0 + tm * 4 + x;
        #pragma unroll
        for (int y = 0; y < 4; y++) {
            const int c = n0 + tn * 4 + y;
            float v = acc[x][y] + bias[c];
            if (MODE == 0) {
                Cout[(size_t)r * N + c] = v;
            } else {
                const int qsel = c >> 10;          // 0=q 1=k 2=v
                const int e = c & 1023;
                const int head = e >> 6;
                const int d = e & 63;
                const int node = r >> 3;
                const int graph = r & 7;
                const int b = graph * NHEADS + head;
                const size_t idx = ((size_t)b * N_NODE + node) * HD + d;
                if (qsel == 0)      Cq[idx] = __float2bfloat16(v * 0.125f);
                else if (qsel == 1) Ck[idx] = __float2bfloat16(v);
                else                Cv[idx] = __float2bfloat16(v);
            }
        }
    }
}

// ---------------- V transpose: [GH][512][64] -> [GH][64][512] ----------------
__global__ __launch_bounds__(256)
void transpose_v(const __hip_bfloat16* __restrict__ V,
                 __hip_bfloat16* __restrict__ Vt)
{
    __shared__ short T[64][80];   // row stride 160B -> rows offset 8 banks (2-way max)
    const int b = blockIdx.y;
    const int jt = blockIdx.x;    // 8 tiles of 64 j
    const int t = threadIdx.x;

    #pragma unroll
    for (int it = 0; it < 2; it++) {
        const int idx = t + it * 256;          // 0..511
        const int j_loc = idx >> 3;            // 0..63
        const int ch = idx & 7;                // 8 bf16 chunk
        bf16x8 v = *reinterpret_cast<const bf16x8*>(
            V + ((size_t)b * N_NODE + jt * 64 + j_loc) * HD + ch * 8);
        *reinterpret_cast<bf16x8*>(&T[j_loc][ch * 8]) = v;
    }
    __syncthreads();
    #pragma unroll
    for (int it = 0; it < 2; it++) {
        const int idx = t + it * 256;
        const int d_loc = idx >> 3;            // 0..63
        const int ch = idx & 7;                // j chunk
        bf16x8 o;
        #pragma unroll
        for (int x = 0; x < 8; x++) o[x] = T[ch * 8 + x][d_loc];
        *reinterpret_cast<bf16x8*>(
            Vt + ((size_t)b * HD + d_loc) * N_NODE + jt * 64 + ch * 8) = o;
    }
}

// ---------------- MFMA attention -------------------------------------------
// Grid: (16 i-tiles of 32, 128 b). Block 256 = 4 waves.
// Q,K: [GH][512][64] bf16 (Q pre-scaled). Vt: [GH][64][512] bf16.
// bias,gaw fp32 [GH][512][512]. A2 out bf16 [512][8][1024].
#define SS 516   // S row stride in floats (pad 4: rows offset 4 banks -> 2-way max, 16B aligned)

__global__ __launch_bounds__(256)
void attn_mfma(const __hip_bfloat16* __restrict__ Qh,
               const __hip_bfloat16* __restrict__ Kh,
               const __hip_bfloat16* __restrict__ Vt,
               const float* __restrict__ bias,
               const float* __restrict__ gaw,
               __hip_bfloat16* __restrict__ A2)
{
    __shared__ float S[32][SS];
    __shared__ float rrs[32];

    const int b  = blockIdx.y;
    const int i0 = blockIdx.x * 32;
    const int tid  = threadIdx.x;
    const int lane = tid & 63;
    const int w    = tid >> 6;
    const int quad = lane >> 4;
    const int l16  = lane & 15;

    // ---- phase 1: S = Q Kt + bias ----
    {
        const int i16 = w & 1;
        const int jh  = w >> 1;
        const __hip_bfloat16* Qb =
            Qh + ((size_t)b * N_NODE + i0 + i16 * 16 + l16) * HD + quad * 8;
        const bf16x8 qa0 = *reinterpret_cast<const bf16x8*>(Qb);
        const bf16x8 qa1 = *reinterpret_cast<const bf16x8*>(Qb + 32);
        const int row_l = i16 * 16 + quad * 4;
        const float* bp0 = bias + ((size_t)b * N_NODE + i0 + row_l) * N_NODE + l16;

        #pragma unroll 4
        for (int jt = jh; jt < 32; jt += 2) {
            const __hip_bfloat16* Kb =
                Kh + ((size_t)b * N_NODE + jt * 16 + l16) * HD + quad * 8;
            const bf16x8 k0 = *reinterpret_cast<const bf16x8*>(Kb);
            const bf16x8 k1 = *reinterpret_cast<const bf16x8*>(Kb + 32);
            f32x4 acc = {0.f, 0.f, 0.f, 0.f};
            acc = __builtin_amdgcn_mfma_f32_16x16x32_bf16(qa0, k0, acc, 0, 0, 0);
            acc = __builtin_amdgcn_mfma_f32_16x16x32_bf16(qa1, k1, acc, 0, 0, 0);
            const float* bp = bp0 + jt * 16;
            #pragma unroll
            for (int r = 0; r < 4; r++)
                S[row_l + r][jt * 16 + l16] = acc[r] + bp[(size_t)r * N_NODE];
        }
    }
    __syncthreads();

    // ---- phase 2: softmax stats (8 threads per row) ----
    {
        const int r  = tid >> 3;
        const int c8 = tid & 7;
        float m = -1e30f;
        #pragma unroll 8
        for (int jj = 0; jj < 64; jj++) m = fmaxf(m, S[r][c8 + 8 * jj]);
        m = fmaxf(m, __shfl_xor(m, 1));
        m = fmaxf(m, __shfl_xor(m, 2));
        m = fmaxf(m, __shfl_xor(m, 4));
        float sum = 0.f;
        #pragma unroll 8
        for (int jj = 0; jj < 64; jj++) {
            const float e = __expf(S[r][c8 + 8 * jj] - m);
            S[r][c8 + 8 * jj] = e;
            sum += e;
        }
        sum += __shfl_xor(sum, 1);
        sum += __shfl_xor(sum, 2);
        sum += __shfl_xor(sum, 4);
        if (c8 == 0) rrs[r] = 1.f / sum;
    }
    __syncthreads();

    // ---- phase 3: P = tanh(gaw) * e * (1/l), in place (fp32) ----
    {
        const float* gb = gaw + ((size_t)b * N_NODE + i0) * N_NODE;  // flat 32*512
        #pragma unroll 4
        for (int it = 0; it < 16; it++) {
            const int idx = tid * 4 + it * 1024;
            const int r = idx >> 9;
            const int j = idx & 511;
            const float4 g = *reinterpret_cast<const float4*>(gb + idx);
            float4 sv = *reinterpret_cast<const float4*>(&S[r][j]);
            const float rs = rrs[r];
            sv.x = tanhf(g.x) * sv.x * rs;
            sv.y = tanhf(g.y) * sv.y * rs;
            sv.z = tanhf(g.z) * sv.z * rs;
            sv.w = tanhf(g.w) * sv.w * rs;
            *reinterpret_cast<float4*>(&S[r][j]) = sv;
        }
    }
    __syncthreads();

    // ---- phase 4: O = P V via MFMA ----
    {
        const int i16 = w & 1;
        #pragma unroll
        for (int dt = 0; dt < 2; dt++) {
            const int d16 = (w >> 1) * 2 + dt;
            const __hip_bfloat16* Vb =
                Vt + ((size_t)b * HD + d16 * 16 + l16) * N_NODE + quad * 8;
            f32x4 acc = {0.f, 0.f, 0.f, 0.f};
            #pragma unroll 4
            for (int j32 = 0; j32 < 16; j32++) {
                const float* sp = &S[i16 * 16 + l16][j32 * 32 + quad * 8];
                bf16x8 af;
                #pragma unroll
                for (int x = 0; x < 8; x++) af[x] = f2bs(sp[x]);
                const bf16x8 bfr = *reinterpret_cast<const bf16x8*>(Vb + j32 * 32);
                acc = __builtin_amdgcn_mfma_f32_16x16x32_bf16(af, bfr, acc, 0, 0, 0);
            }
            const int node0 = i0 + i16 * 16 + quad * 4;
            __hip_bfloat16* op = A2 + (size_t)node0 * (N_GRAPH * EDIM)
                               + (b >> 4) * EDIM + (b & 15) * HD + d16 * 16 + l16;
            #pragma unroll
            for (int r = 0; r < 4; r++)
                op[(size_t)r * (N_GRAPH * EDIM)] = __float2bfloat16(acc[r]);
        }
    }
}

extern "C" void kernel_launch(void* const* d_in, const int* in_sizes, int n_in,
                              void* d_out, int out_size, void* d_ws, size_t ws_size,
                              hipStream_t stream) {
    const float* query     = (const float*)d_in[0];
    const float* attn_bias = (const float*)d_in[1];
    const float* gaw       = (const float*)d_in[2];
    const float* in_w      = (const float*)d_in[3];
    const float* in_b      = (const float*)d_in[4];
    const float* out_w     = (const float*)d_in[5];
    const float* out_b     = (const float*)d_in[6];
    float* out = (float*)d_out;

    __hip_bfloat16* ws = (__hip_bfloat16*)d_ws;
    const size_t hsz = (size_t)GH * N_NODE * HD;   // 4 Mi elements
    __hip_bfloat16* Q  = ws;
    __hip_bfloat16* K  = ws + hsz;
    __hip_bfloat16* V  = ws + 2 * hsz;
    __hip_bfloat16* Vt = ws + 3 * hsz;
    __hip_bfloat16* A2 = V;   // alias: V dead after transpose

    // 1) fused QKV projection + head-layout scatter (bf16 out)
    {
        dim3 grid((3 * EDIM) / 64, MROWS / 64);
        gemm_nt<float, 1><<<grid, 256, 0, stream>>>(query, in_w, in_b,
                                                    nullptr, Q, K, V,
                                                    MROWS, 3 * EDIM, EDIM);
    }
    // 2) V -> Vt
    {
        dim3 grid(8, GH);
        transpose_v<<<grid, 256, 0, stream>>>(V, Vt);
    }
    // 3) MFMA attention (writes A2, aliasing V)
    {
        dim3 grid(N_NODE / 32, GH);
        attn_mfma<<<grid, 256, 0, stream>>>(Q, K, Vt, attn_bias, gaw, A2);
    }
    // 4) output projection
    {
        dim3 grid(EDIM / 64, MROWS / 64);
        gemm_nt<__hip_bfloat16, 0><<<grid, 256, 0, stream>>>(A2, out_w, out_b,
                                                             out, nullptr, nullptr, nullptr,
                                                             MROWS, EDIM, EDIM);
    }
}

// Round 5
// 515.619 us; speedup vs baseline: 4.8753x; 1.9768x over previous
//
#include <hip/hip_runtime.h>
#include <hip/hip_bf16.h>

#define N_NODE 512
#define N_GRAPH 8
#define EDIM 1024
#define NHEADS 16
#define HD 64
#define GH 128       // n_graph * NHEADS
#define MROWS 4096   // n_node * n_graph

typedef short bf16x8 __attribute__((ext_vector_type(8)));
typedef float f32x4  __attribute__((ext_vector_type(4)));

__device__ __forceinline__ float bf2f(__hip_bfloat16 h) { return __bfloat162float(h); }
__device__ __forceinline__ short f2bs(float f) {
    union { __hip_bfloat16 h; short s; } u; u.h = __float2bfloat16(f); return u.s;
}

// ---------------- staging helpers: 16 elements -> 16 bf16 in LDS ------------
__device__ __forceinline__ void stage16(short* l, const float* g) {
    const float4 f0 = *reinterpret_cast<const float4*>(g);
    const float4 f1 = *reinterpret_cast<const float4*>(g + 4);
    const float4 f2 = *reinterpret_cast<const float4*>(g + 8);
    const float4 f3 = *reinterpret_cast<const float4*>(g + 12);
    bf16x8 h0, h1;
    h0[0]=f2bs(f0.x); h0[1]=f2bs(f0.y); h0[2]=f2bs(f0.z); h0[3]=f2bs(f0.w);
    h0[4]=f2bs(f1.x); h0[5]=f2bs(f1.y); h0[6]=f2bs(f1.z); h0[7]=f2bs(f1.w);
    h1[0]=f2bs(f2.x); h1[1]=f2bs(f2.y); h1[2]=f2bs(f2.z); h1[3]=f2bs(f2.w);
    h1[4]=f2bs(f3.x); h1[5]=f2bs(f3.y); h1[6]=f2bs(f3.z); h1[7]=f2bs(f3.w);
    *reinterpret_cast<bf16x8*>(l)     = h0;
    *reinterpret_cast<bf16x8*>(l + 8) = h1;
}
__device__ __forceinline__ void stage16(short* l, const __hip_bfloat16* g) {
    *reinterpret_cast<bf16x8*>(l)     = *reinterpret_cast<const bf16x8*>(g);
    *reinterpret_cast<bf16x8*>(l + 8) = *reinterpret_cast<const bf16x8*>(g + 8);
}

// ---------------- MFMA GEMM: C = A @ B^T + bias -----------------------------
// A [M,K] row-major (fp32 or bf16), B [N,K] row-major fp32. 128x128 tile, BK=32.
// MODE 0: C row-major [M,N] fp32 into Cout.
// MODE 1: qkv scatter into Cq/Ck/Cv bf16 [GH][N_NODE][HD]; q scaled 0.125.
#define LDST 40   // LDS row stride in shorts (80 B: 16B-aligned, 2-way bank alias = free)

template<typename TA, int MODE>
__global__ __launch_bounds__(256)
void gemm_mfma(const TA* __restrict__ A,
               const float* __restrict__ B,
               const float* __restrict__ bias,
               float* __restrict__ Cout,
               __hip_bfloat16* __restrict__ Cq,
               __hip_bfloat16* __restrict__ Ck,
               __hip_bfloat16* __restrict__ Cv,
               int M, int N, int K)
{
    __shared__ short As[128 * LDST];
    __shared__ short Bs[128 * LDST];

    const int tid  = threadIdx.x;
    const int m0   = blockIdx.y * 128;
    const int n0   = blockIdx.x * 128;
    const int lane = tid & 63;
    const int w    = tid >> 6;
    const int l16  = lane & 15;
    const int quad = lane >> 4;
    const int wm   = w & 1;
    const int wn   = w >> 1;
    const int srow  = tid >> 1;          // 0..127 staging row
    const int shalf = (tid & 1) * 16;    // 0 or 16

    f32x4 acc[4][4];
    #pragma unroll
    for (int mt = 0; mt < 4; mt++)
        #pragma unroll
        for (int nt = 0; nt < 4; nt++)
            acc[mt][nt] = (f32x4){0.f, 0.f, 0.f, 0.f};

    for (int k0 = 0; k0 < K; k0 += 32) {
        stage16(&As[srow * LDST + shalf], A + (size_t)(m0 + srow) * K + k0 + shalf);
        stage16(&Bs[srow * LDST + shalf], B + (size_t)(n0 + srow) * K + k0 + shalf);
        __syncthreads();

        bf16x8 af[4], bfr[4];
        #pragma unroll
        for (int mt = 0; mt < 4; mt++)
            af[mt] = *reinterpret_cast<const bf16x8*>(
                &As[(wm * 64 + mt * 16 + l16) * LDST + quad * 8]);
        #pragma unroll
        for (int nt = 0; nt < 4; nt++)
            bfr[nt] = *reinterpret_cast<const bf16x8*>(
                &Bs[(wn * 64 + nt * 16 + l16) * LDST + quad * 8]);
        #pragma unroll
        for (int mt = 0; mt < 4; mt++)
            #pragma unroll
            for (int nt = 0; nt < 4; nt++)
                acc[mt][nt] = __builtin_amdgcn_mfma_f32_16x16x32_bf16(
                    af[mt], bfr[nt], acc[mt][nt], 0, 0, 0);
        __syncthreads();
    }

    // epilogue: C[m = quad*4+reg (+tile offsets)][n = l16 (+tile offsets)]
    #pragma unroll
    for (int nt = 0; nt < 4; nt++) {
        const int c = n0 + wn * 64 + nt * 16 + l16;
        const float bv = bias[c];
        #pragma unroll
        for (int mt = 0; mt < 4; mt++) {
            #pragma unroll
            for (int rr = 0; rr < 4; rr++) {
                const int r = m0 + wm * 64 + mt * 16 + quad * 4 + rr;
                const float v = acc[mt][nt][rr] + bv;
                if (MODE == 0) {
                    Cout[(size_t)r * N + c] = v;
                } else {
                    const int qsel = c >> 10;          // 0=q 1=k 2=v
                    const int e = c & 1023;
                    const int head = e >> 6;
                    const int d = e & 63;
                    const int node = r >> 3;
                    const int graph = r & 7;
                    const int b = graph * NHEADS + head;
                    const size_t idx = ((size_t)b * N_NODE + node) * HD + d;
                    if (qsel == 0)      Cq[idx] = __float2bfloat16(v * 0.125f);
                    else if (qsel == 1) Ck[idx] = __float2bfloat16(v);
                    else                Cv[idx] = __float2bfloat16(v);
                }
            }
        }
    }
}

// ---------------- V transpose: [GH][512][64] -> [GH][64][512] ----------------
__global__ __launch_bounds__(256)
void transpose_v(const __hip_bfloat16* __restrict__ V,
                 __hip_bfloat16* __restrict__ Vt)
{
    __shared__ short T[64][80];
    const int b = blockIdx.y;
    const int jt = blockIdx.x;    // 8 tiles of 64 j
    const int t = threadIdx.x;

    #pragma unroll
    for (int it = 0; it < 2; it++) {
        const int idx = t + it * 256;          // 0..511
        const int j_loc = idx >> 3;
        const int ch = idx & 7;
        bf16x8 v = *reinterpret_cast<const bf16x8*>(
            V + ((size_t)b * N_NODE + jt * 64 + j_loc) * HD + ch * 8);
        *reinterpret_cast<bf16x8*>(&T[j_loc][ch * 8]) = v;
    }
    __syncthreads();
    #pragma unroll
    for (int it = 0; it < 2; it++) {
        const int idx = t + it * 256;
        const int d_loc = idx >> 3;
        const int ch = idx & 7;
        bf16x8 o;
        #pragma unroll
        for (int x = 0; x < 8; x++) o[x] = T[ch * 8 + x][d_loc];
        *reinterpret_cast<bf16x8*>(
            Vt + ((size_t)b * HD + d_loc) * N_NODE + jt * 64 + ch * 8) = o;
    }
}

// ---------------- MFMA attention (unchanged from R4) -------------------------
#define SS 516

__global__ __launch_bounds__(256)
void attn_mfma(const __hip_bfloat16* __restrict__ Qh,
               const __hip_bfloat16* __restrict__ Kh,
               const __hip_bfloat16* __restrict__ Vt,
               const float* __restrict__ bias,
               const float* __restrict__ gaw,
               __hip_bfloat16* __restrict__ A2)
{
    __shared__ float S[32][SS];
    __shared__ float rrs[32];

    const int b  = blockIdx.y;
    const int i0 = blockIdx.x * 32;
    const int tid  = threadIdx.x;
    const int lane = tid & 63;
    const int w    = tid >> 6;
    const int quad = lane >> 4;
    const int l16  = lane & 15;

    // ---- phase 1: S = Q Kt + bias ----
    {
        const int i16 = w & 1;
        const int jh  = w >> 1;
        const __hip_bfloat16* Qb =
            Qh + ((size_t)b * N_NODE + i0 + i16 * 16 + l16) * HD + quad * 8;
        const bf16x8 qa0 = *reinterpret_cast<const bf16x8*>(Qb);
        const bf16x8 qa1 = *reinterpret_cast<const bf16x8*>(Qb + 32);
        const int row_l = i16 * 16 + quad * 4;
        const float* bp0 = bias + ((size_t)b * N_NODE + i0 + row_l) * N_NODE + l16;

        #pragma unroll 4
        for (int jt = jh; jt < 32; jt += 2) {
            const __hip_bfloat16* Kb =
                Kh + ((size_t)b * N_NODE + jt * 16 + l16) * HD + quad * 8;
            const bf16x8 k0 = *reinterpret_cast<const bf16x8*>(Kb);
            const bf16x8 k1 = *reinterpret_cast<const bf16x8*>(Kb + 32);
            f32x4 acc = {0.f, 0.f, 0.f, 0.f};
            acc = __builtin_amdgcn_mfma_f32_16x16x32_bf16(qa0, k0, acc, 0, 0, 0);
            acc = __builtin_amdgcn_mfma_f32_16x16x32_bf16(qa1, k1, acc, 0, 0, 0);
            const float* bp = bp0 + jt * 16;
            #pragma unroll
            for (int r = 0; r < 4; r++)
                S[row_l + r][jt * 16 + l16] = acc[r] + bp[(size_t)r * N_NODE];
        }
    }
    __syncthreads();

    // ---- phase 2: softmax stats ----
    {
        const int r  = tid >> 3;
        const int c8 = tid & 7;
        float m = -1e30f;
        #pragma unroll 8
        for (int jj = 0; jj < 64; jj++) m = fmaxf(m, S[r][c8 + 8 * jj]);
        m = fmaxf(m, __shfl_xor(m, 1));
        m = fmaxf(m, __shfl_xor(m, 2));
        m = fmaxf(m, __shfl_xor(m, 4));
        float sum = 0.f;
        #pragma unroll 8
        for (int jj = 0; jj < 64; jj++) {
            const float e = __expf(S[r][c8 + 8 * jj] - m);
            S[r][c8 + 8 * jj] = e;
            sum += e;
        }
        sum += __shfl_xor(sum, 1);
        sum += __shfl_xor(sum, 2);
        sum += __shfl_xor(sum, 4);
        if (c8 == 0) rrs[r] = 1.f / sum;
    }
    __syncthreads();

    // ---- phase 3: P = tanh(gaw) * e * (1/l) ----
    {
        const float* gb = gaw + ((size_t)b * N_NODE + i0) * N_NODE;
        #pragma unroll 4
        for (int it = 0; it < 16; it++) {
            const int idx = tid * 4 + it * 1024;
            const int r = idx >> 9;
            const int j = idx & 511;
            const float4 g = *reinterpret_cast<const float4*>(gb + idx);
            float4 sv = *reinterpret_cast<const float4*>(&S[r][j]);
            const float rs = rrs[r];
            sv.x = tanhf(g.x) * sv.x * rs;
            sv.y = tanhf(g.y) * sv.y * rs;
            sv.z = tanhf(g.z) * sv.z * rs;
            sv.w = tanhf(g.w) * sv.w * rs;
            *reinterpret_cast<float4*>(&S[r][j]) = sv;
        }
    }
    __syncthreads();

    // ---- phase 4: O = P V ----
    {
        const int i16 = w & 1;
        #pragma unroll
        for (int dt = 0; dt < 2; dt++) {
            const int d16 = (w >> 1) * 2 + dt;
            const __hip_bfloat16* Vb =
                Vt + ((size_t)b * HD + d16 * 16 + l16) * N_NODE + quad * 8;
            f32x4 acc = {0.f, 0.f, 0.f, 0.f};
            #pragma unroll 4
            for (int j32 = 0; j32 < 16; j32++) {
                const float* sp = &S[i16 * 16 + l16][j32 * 32 + quad * 8];
                bf16x8 af;
                #pragma unroll
                for (int x = 0; x < 8; x++) af[x] = f2bs(sp[x]);
                const bf16x8 bfr = *reinterpret_cast<const bf16x8*>(Vb + j32 * 32);
                acc = __builtin_amdgcn_mfma_f32_16x16x32_bf16(af, bfr, acc, 0, 0, 0);
            }
            const int node0 = i0 + i16 * 16 + quad * 4;
            __hip_bfloat16* op = A2 + (size_t)node0 * (N_GRAPH * EDIM)
                               + (b >> 4) * EDIM + (b & 15) * HD + d16 * 16 + l16;
            #pragma unroll
            for (int r = 0; r < 4; r++)
                op[(size_t)r * (N_GRAPH * EDIM)] = __float2bfloat16(acc[r]);
        }
    }
}

extern "C" void kernel_launch(void* const* d_in, const int* in_sizes, int n_in,
                              void* d_out, int out_size, void* d_ws, size_t ws_size,
                              hipStream_t stream) {
    const float* query     = (const float*)d_in[0];
    const float* attn_bias = (const float*)d_in[1];
    const float* gaw       = (const float*)d_in[2];
    const float* in_w      = (const float*)d_in[3];
    const float* in_b      = (const float*)d_in[4];
    const float* out_w     = (const float*)d_in[5];
    const float* out_b     = (const float*)d_in[6];
    float* out = (float*)d_out;

    __hip_bfloat16* ws = (__hip_bfloat16*)d_ws;
    const size_t hsz = (size_t)GH * N_NODE * HD;   // 4 Mi elements
    __hip_bfloat16* Q  = ws;
    __hip_bfloat16* K  = ws + hsz;
    __hip_bfloat16* V  = ws + 2 * hsz;
    __hip_bfloat16* Vt = ws + 3 * hsz;
    __hip_bfloat16* A2 = V;   // alias: V dead after transpose

    // 1) fused QKV projection + head-layout scatter (MFMA)
    {
        dim3 grid((3 * EDIM) / 128, MROWS / 128);   // (24, 32)
        gemm_mfma<float, 1><<<grid, 256, 0, stream>>>(query, in_w, in_b,
                                                      nullptr, Q, K, V,
                                                      MROWS, 3 * EDIM, EDIM);
    }
    // 2) V -> Vt
    {
        dim3 grid(8, GH);
        transpose_v<<<grid, 256, 0, stream>>>(V, Vt);
    }
    // 3) MFMA attention
    {
        dim3 grid(N_NODE / 32, GH);
        attn_mfma<<<grid, 256, 0, stream>>>(Q, K, Vt, attn_bias, gaw, A2);
    }
    // 4) output projection (MFMA)
    {
        dim3 grid(EDIM / 128, MROWS / 128);         // (8, 32)
        gemm_mfma<__hip_bfloat16, 0><<<grid, 256, 0, stream>>>(A2, out_w, out_b,
                                                               out, nullptr, nullptr, nullptr,
                                                               MROWS, EDIM, EDIM);
    }
}